// Round 3
// 948.481 us; speedup vs baseline: 1.1148x; 1.1148x over previous
//
#include <hip/hip_runtime.h>
#include <math.h>

#define NB 8
#define NV 100
#define LQ 128
#define NKG 923
#define NT 1024
#define DV 2048
#define DK 300
#define DH 1024
#define NH 8
#define DHD 128
#define NLAYERS 3

typedef __attribute__((ext_vector_type(8))) short short8;
typedef __attribute__((ext_vector_type(4))) float f32x4;

__device__ __forceinline__ short f2bf(float f) {
    unsigned u = __float_as_uint(f);
    u += 0x7fff + ((u >> 16) & 1);   // round-to-nearest-even
    return (short)(u >> 16);
}
__device__ __forceinline__ float bf2f(short s) {
    unsigned u = ((unsigned)(unsigned short)s) << 16;
    return __uint_as_float(u);
}
__device__ __forceinline__ unsigned pack2(float a, float b) {
    return (unsigned)(unsigned short)f2bf(a) | ((unsigned)(unsigned short)f2bf(b) << 16);
}

#if __has_builtin(__builtin_amdgcn_global_load_lds)
#define HAVE_GLL 1
__device__ __forceinline__ void gll16(const void* g, void* l) {
    __builtin_amdgcn_global_load_lds(
        (const __attribute__((address_space(1))) void*)g,
        (__attribute__((address_space(3))) void*)l, 16, 0, 0);
}
#else
#define HAVE_GLL 0
#endif

// ---------------- fast block reductions (blockDim.x == 256, 4 waves) -------
__device__ __forceinline__ float block_sum1(float a, float* red4) {
#pragma unroll
    for (int off = 32; off > 0; off >>= 1) a += __shfl_xor(a, off, 64);
    int w = threadIdx.x >> 6;
    if ((threadIdx.x & 63) == 0) red4[w] = a;
    __syncthreads();
    return red4[0] + red4[1] + red4[2] + red4[3];
}
__device__ __forceinline__ float block_max1(float a, float* red4) {
#pragma unroll
    for (int off = 32; off > 0; off >>= 1) a = fmaxf(a, __shfl_xor(a, off, 64));
    int w = threadIdx.x >> 6;
    if ((threadIdx.x & 63) == 0) red4[w] = a;
    __syncthreads();
    return fmaxf(fmaxf(red4[0], red4[1]), fmaxf(red4[2], red4[3]));
}
__device__ __forceinline__ float2 block_sum2(float a, float b, float* red8) {
#pragma unroll
    for (int off = 32; off > 0; off >>= 1) {
        a += __shfl_xor(a, off, 64);
        b += __shfl_xor(b, off, 64);
    }
    int w = threadIdx.x >> 6;
    if ((threadIdx.x & 63) == 0) { red8[w] = a; red8[4 + w] = b; }
    __syncthreads();
    float2 r;
    r.x = red8[0] + red8[1] + red8[2] + red8[3];
    r.y = red8[4] + red8[5] + red8[6] + red8[7];
    return r;
}

// ---------------- adjacency -> bitmask ----------------
__global__ __launch_bounds__(256) void bitmask_kernel(
    const int* __restrict__ adj, unsigned* __restrict__ mb)
{
    int bi = blockIdx.x;
    int tid = threadIdx.x;
#pragma unroll
    for (int p = 0; p < 4; ++p) {
        int j = p * 256 + tid;
        unsigned long long bal = __ballot(adj[(size_t)bi * NT + j] > 0);
        if ((tid & 63) == 0) {
            int w = (p * 256 + (tid & 0xC0)) >> 5;
            mb[(size_t)bi * 32 + w]     = (unsigned)bal;
            mb[(size_t)bi * 32 + w + 1] = (unsigned)(bal >> 32);
        }
    }
}

// ---------------- weight transpose-cast: out[N,Kp] bf16 <- in[K,N] fp32 ----
// batched over blockIdx.z via strides (gat stack in one launch)
__global__ __launch_bounds__(256) void transpose_cast(
    const float* __restrict__ in, short* __restrict__ out,
    int K, int N, int Kp, size_t in_stride, size_t out_stride)
{
    __shared__ float ls[64][65];
    const float* inL = in + (size_t)blockIdx.z * in_stride;
    short* outL = out + (size_t)blockIdx.z * out_stride;
    int n0 = blockIdx.x * 64, k0 = blockIdx.y * 64;
    int tid = threadIdx.x;
    int j4 = (tid & 15) * 4;
#pragma unroll
    for (int s = 0; s < 4; ++s) {
        int i = (tid >> 4) + s * 16;
        int k = k0 + i;
        float4 v = make_float4(0.f, 0.f, 0.f, 0.f);
        if (k < K) v = *(const float4*)(inL + (size_t)k * N + n0 + j4);
        ls[i][j4 + 0] = v.x; ls[i][j4 + 1] = v.y;
        ls[i][j4 + 2] = v.z; ls[i][j4 + 3] = v.w;
    }
    __syncthreads();
#pragma unroll
    for (int s = 0; s < 4; ++s) {
        int a = (tid >> 4) + s * 16;
        int b = (tid & 15) * 4;
        uint2 pk;
        pk.x = pack2(ls[b + 0][a], ls[b + 1][a]);
        pk.y = pack2(ls[b + 2][a], ls[b + 3][a]);
        *(uint2*)(outL + (size_t)(n0 + a) * Kp + k0 + b) = pk;
    }
}

// ---------------- MFMA GEMM (fp32 A): C = A @ Wt^T + bias  (projections) ---
__global__ __launch_bounds__(256) void gemm_bias_mfma(
    const float* __restrict__ A, const short* __restrict__ Wt,
    const float* __restrict__ bias, float* __restrict__ C,
    int M, int N, int K, int Kp, int ldA)
{
    __shared__ short At[128][32];
    __shared__ short Bt[128][32];
    int tid = threadIdx.x;
    int row0 = blockIdx.y * 128, col0 = blockIdx.x * 128;
    int lane = tid & 63, wave = tid >> 6;
    int quad = lane >> 4, lq = lane & 15;
    int wm = (wave >> 1) * 64, wn = (wave & 1) * 64;
    f32x4 acc[4][4];
#pragma unroll
    for (int i = 0; i < 4; ++i)
#pragma unroll
        for (int j = 0; j < 4; ++j) {
            f32x4 z = {0.f, 0.f, 0.f, 0.f};
            acc[i][j] = z;
        }
    int ar = tid >> 2;
    int ac = (tid & 3) * 8;
    for (int k0 = 0; k0 < Kp; k0 += 32) {
        bool fullk = (k0 + 32 <= K);
#pragma unroll
        for (int s = 0; s < 2; ++s) {
            int r = ar + s * 64;
            int grow = row0 + r;
            short8 pk;
            if (grow < M && fullk) {
                const float* src = A + (size_t)grow * ldA + k0 + ac;
                float4 v0 = *(const float4*)(src);
                float4 v1 = *(const float4*)(src + 4);
                pk[0] = f2bf(v0.x); pk[1] = f2bf(v0.y);
                pk[2] = f2bf(v0.z); pk[3] = f2bf(v0.w);
                pk[4] = f2bf(v1.x); pk[5] = f2bf(v1.y);
                pk[6] = f2bf(v1.z); pk[7] = f2bf(v1.w);
            } else {
#pragma unroll
                for (int e = 0; e < 8; ++e) {
                    int k = k0 + ac + e;
                    pk[e] = (grow < M && k < K)
                          ? f2bf(A[(size_t)grow * ldA + k]) : (short)0;
                }
            }
            *(short8*)&At[r][ac] = pk;
        }
#pragma unroll
        for (int s = 0; s < 2; ++s) {
            int n = ar + s * 64;
            short8 w = *(const short8*)(Wt + (size_t)(col0 + n) * Kp + k0 + ac);
            *(short8*)&Bt[n][ac] = w;
        }
        __syncthreads();
        short8 af[4], bfr[4];
#pragma unroll
        for (int i = 0; i < 4; ++i)
            af[i] = *(short8*)&At[wm + i * 16 + lq][quad * 8];
#pragma unroll
        for (int j = 0; j < 4; ++j)
            bfr[j] = *(short8*)&Bt[wn + j * 16 + lq][quad * 8];
#pragma unroll
        for (int i = 0; i < 4; ++i)
#pragma unroll
            for (int j = 0; j < 4; ++j)
                acc[i][j] = __builtin_amdgcn_mfma_f32_16x16x32_bf16(
                    af[i], bfr[j], acc[i][j], 0, 0, 0);
        __syncthreads();
    }
#pragma unroll
    for (int j = 0; j < 4; ++j) {
        int n = col0 + wn + j * 16 + lq;
        float bv = bias[n];
#pragma unroll
        for (int i = 0; i < 4; ++i) {
#pragma unroll
            for (int r = 0; r < 4; ++r) {
                int m = row0 + wm + i * 16 + quad * 4 + r;
                if (m < M) C[(size_t)m * N + n] = acc[i][j][r] + bv;
            }
        }
    }
}

// ---------------- fused GAT gemm: h = xb@W^T+b, writes ht (bf16 [d][j]) + s,t
// grid (NH, M/128). LDS: ct aliases At/Bt (dead after K-loop) -> ~38 KB.
__global__ __launch_bounds__(256) void gemm_st_mfma(
    const short* __restrict__ Ab, const short* __restrict__ Wt,
    const float* __restrict__ bias,
    const float* __restrict__ asrc, const float* __restrict__ adst,
    short* __restrict__ ht,
    float* __restrict__ sbuf, float* __restrict__ tbuf)
{
    __shared__ __align__(16) short smem[17408];   // 34816 B
    short (*At)[32]  = (short(*)[32])smem;         // 8 KB (K-loop)
    short (*Bt)[32]  = (short(*)[32])(smem + 4096);// 8 KB (K-loop)
    short (*ct)[136] = (short(*)[136])smem;        // 34.8 KB (epilogue, aliases)
    __shared__ float sred[2][128], tred[2][128];
    __shared__ float asl[128], adl[128];
    int tid = threadIdx.x;
    int h = blockIdx.x;
    int row0 = blockIdx.y * 128, col0 = h * 128;
    int b = row0 >> 10, i0 = row0 & 1023;
    int lane = tid & 63, wave = tid >> 6;
    int quad = lane >> 4, lq = lane & 15;
    int wm = (wave >> 1) * 64, wn = (wave & 1) * 64;
    if (tid < 128) asl[tid] = asrc[h * DHD + tid];
    else adl[tid - 128] = adst[h * DHD + tid - 128];
    f32x4 acc[4][4];
#pragma unroll
    for (int i = 0; i < 4; ++i)
#pragma unroll
        for (int j = 0; j < 4; ++j) {
            f32x4 z = {0.f, 0.f, 0.f, 0.f};
            acc[i][j] = z;
        }

    const short* gA0 = Ab + (size_t)(row0 + wave * 16 + (lane >> 2)) * DH + (lane & 3) * 8;
    const short* gA1 = gA0 + (size_t)64 * DH;
    const short* gB0 = Wt + (size_t)(col0 + wave * 16 + (lane >> 2)) * DH + (lane & 3) * 8;
    const short* gB1 = gB0 + (size_t)64 * DH;
#if HAVE_GLL
    char* lA0 = (char*)At + wave * 1024; char* lA1 = lA0 + 4096;
    char* lB0 = (char*)Bt + wave * 1024; char* lB1 = lB0 + 4096;
#endif
    for (int k0 = 0; k0 < DH; k0 += 32) {
#if HAVE_GLL
        gll16(gA0 + k0, lA0); gll16(gA1 + k0, lA1);
        gll16(gB0 + k0, lB0); gll16(gB1 + k0, lB1);
#else
        {
            short8 va0 = *(const short8*)(gA0 + k0);
            short8 va1 = *(const short8*)(gA1 + k0);
            short8 vb0 = *(const short8*)(gB0 + k0);
            short8 vb1 = *(const short8*)(gB1 + k0);
            *(short8*)((char*)At + wave * 1024 + lane * 16) = va0;
            *(short8*)((char*)At + 4096 + wave * 1024 + lane * 16) = va1;
            *(short8*)((char*)Bt + wave * 1024 + lane * 16) = vb0;
            *(short8*)((char*)Bt + 4096 + wave * 1024 + lane * 16) = vb1;
        }
#endif
        __syncthreads();
        short8 af[4], bfr[4];
#pragma unroll
        for (int i = 0; i < 4; ++i)
            af[i] = *(short8*)&At[wm + i * 16 + lq][quad * 8];
#pragma unroll
        for (int j = 0; j < 4; ++j)
            bfr[j] = *(short8*)&Bt[wn + j * 16 + lq][quad * 8];
#pragma unroll
        for (int i = 0; i < 4; ++i)
#pragma unroll
            for (int j = 0; j < 4; ++j)
                acc[i][j] = __builtin_amdgcn_mfma_f32_16x16x32_bf16(
                    af[i], bfr[j], acc[i][j], 0, 0, 0);
        __syncthreads();
    }
    // epilogue 1: bias + bf16, store transposed tile ct[d][i] (aliases At/Bt)
#pragma unroll
    for (int j = 0; j < 4; ++j) {
        int d = wn + j * 16 + lq;
        float bv = bias[col0 + d];
#pragma unroll
        for (int i2 = 0; i2 < 4; ++i2) {
            int m = wm + i2 * 16 + quad * 4;
            uint2 pk;
            pk.x = pack2(acc[i2][j][0] + bv, acc[i2][j][1] + bv);
            pk.y = pack2(acc[i2][j][2] + bv, acc[i2][j][3] + bv);
            *(uint2*)&ct[d][m] = pk;
        }
    }
    __syncthreads();
    // epilogue 2: ht global store
    {
        int d = tid >> 1, half = tid & 1;
        short* dst = ht + ((size_t)(b * NH + h) * DHD + d) * NT + i0 + half * 64;
        const short* src = &ct[d][half * 64];
#pragma unroll
        for (int q = 0; q < 8; ++q)
            *(short8*)(dst + q * 8) = *(const short8*)(src + q * 8);
    }
    // epilogue 3: s,t from ct
    {
        int i = tid >> 1, half = tid & 1;
        float sa = 0.f, ta = 0.f;
#pragma unroll 16
        for (int dd = 0; dd < 64; ++dd) {
            int d = half * 64 + dd;
            float hv = bf2f(ct[d][i]);
            sa += hv * asl[d];
            ta += hv * adl[d];
        }
        sred[half][i] = sa; tred[half][i] = ta;
    }
    __syncthreads();
    if (tid < 128) {
        size_t idx = (size_t)(b * NH + h) * NT + i0 + tid;
        sbuf[idx] = sred[0][tid] + sred[1][tid];
        tbuf[idx] = tred[0][tid] + tred[1][tid];
    }
}

// ---------------- LayerNorm + type-emb add + scatter into x/xb ------------
__global__ __launch_bounds__(256) void ln_scatter(
    const float* __restrict__ src, float* __restrict__ x,
    const float* __restrict__ g, const float* __restrict__ bta,
    const int* __restrict__ types, const float* __restrict__ type_emb,
    short* __restrict__ xb,
    int rows, int npb, int node_off)
{
    __shared__ float red[8];
    int r = blockIdx.x;
    if (r >= rows) return;
    int tid = threadIdx.x;
    int b = r / npb, n = r - b * npb;
    int node = b * NT + node_off + n;
    float4 v = *(const float4*)(src + (size_t)r * DH + tid * 4);
    float s = v.x + v.y + v.z + v.w;
    float sq = v.x * v.x + v.y * v.y + v.z * v.z + v.w * v.w;
    float2 t2 = block_sum2(s, sq, red);
    float mean = t2.x * (1.0f / DH);
    float var = t2.y * (1.0f / DH) - mean * mean;
    float rstd = 1.0f / sqrtf(var + 1e-5f);
    float4 gv = *(const float4*)(g + tid * 4);
    float4 bv = *(const float4*)(bta + tid * 4);
    int ty = types[node];
    float4 tv = *(const float4*)(type_emb + (size_t)ty * DH + tid * 4);
    float4 o;
    o.x = (v.x - mean) * rstd * gv.x + bv.x + tv.x;
    o.y = (v.y - mean) * rstd * gv.y + bv.y + tv.y;
    o.z = (v.z - mean) * rstd * gv.z + bv.z + tv.z;
    o.w = (v.w - mean) * rstd * gv.w + bv.w + tv.w;
    *(float4*)(x + (size_t)node * DH + tid * 4) = o;
    uint2 pk;
    pk.x = pack2(o.x, o.y);
    pk.y = pack2(o.z, o.w);
    *(uint2*)(xb + (size_t)node * DH + tid * 4) = pk;
}

// ---------------- residual+LN (+ optional readout score fused on last layer)
__global__ __launch_bounds__(256) void ln_residual(
    float* __restrict__ x, const float* __restrict__ o,
    const float* __restrict__ g, const float* __restrict__ bta,
    short* __restrict__ xb,
    const float* __restrict__ rW, const float* __restrict__ rb,
    float* __restrict__ scores)
{
    __shared__ float red[12];
    int r = blockIdx.x;
    int tid = threadIdx.x;
    float* xr = x + (size_t)r * DH;
    float4 xv = *(float4*)(xr + tid * 4);
    float4 ov = *(const float4*)(o + (size_t)r * DH + tid * 4);
    float v0 = xv.x + ov.x, v1 = xv.y + ov.y, v2 = xv.z + ov.z, v3 = xv.w + ov.w;
    float s = v0 + v1 + v2 + v3;
    float sq = v0 * v0 + v1 * v1 + v2 * v2 + v3 * v3;
    float2 t2 = block_sum2(s, sq, red);
    float mean = t2.x * (1.0f / DH);
    float var = t2.y * (1.0f / DH) - mean * mean;
    float rstd = 1.0f / sqrtf(var + 1e-5f);
    float4 gv = *(const float4*)(g + tid * 4);
    float4 bv = *(const float4*)(bta + tid * 4);
    float4 out;
    out.x = (v0 - mean) * rstd * gv.x + bv.x;
    out.y = (v1 - mean) * rstd * gv.y + bv.y;
    out.z = (v2 - mean) * rstd * gv.z + bv.z;
    out.w = (v3 - mean) * rstd * gv.w + bv.w;
    *(float4*)(xr + tid * 4) = out;
    uint2 pk;
    pk.x = pack2(out.x, out.y);
    pk.y = pack2(out.z, out.w);
    *(uint2*)(xb + (size_t)r * DH + tid * 4) = pk;
    if (scores) {
        float4 wv = *(const float4*)(rW + tid * 4);
        float p = out.x * wv.x + out.y * wv.y + out.z * wv.z + out.w * wv.w;
        float totp = block_sum1(p, red + 8);
        if (tid == 0) scores[r] = totp + rb[0];
    }
}

// ---------------- text: masked mean pool (partials over 4 token chunks) ----
__global__ __launch_bounds__(256) void qpool_part(
    const float* __restrict__ tok_emb, const int* __restrict__ ids,
    const int* __restrict__ amask, float* __restrict__ ppool,
    float* __restrict__ pden)
{
    int b = blockIdx.x, c = blockIdx.y;
    int tid = threadIdx.x;
    float a0 = 0, a1 = 0, a2 = 0, a3 = 0;
    float denom = 0;
    for (int l = c * 32; l < (c + 1) * 32; ++l) {
        int id = ids[b * LQ + l];
        float m = (float)amask[b * LQ + l];
        denom += m;
        float4 e = *(const float4*)(tok_emb + (size_t)id * DH + tid * 4);
        a0 += m * e.x; a1 += m * e.y; a2 += m * e.z; a3 += m * e.w;
    }
    float4 o = make_float4(a0, a1, a2, a3);
    *(float4*)(ppool + ((size_t)(b * 4 + c)) * DH + tid * 4) = o;
    if (tid == 0) pden[b * 4 + c] = denom;
}
__global__ __launch_bounds__(256) void qpool_fin(
    const float* __restrict__ ppool, const float* __restrict__ pden,
    float* __restrict__ pooled)
{
    int b = blockIdx.x;
    int tid = threadIdx.x;
    float den = pden[b * 4] + pden[b * 4 + 1] + pden[b * 4 + 2] + pden[b * 4 + 3];
    float inv = 1.0f / fmaxf(den, 1.0f);
    float4 s = make_float4(0.f, 0.f, 0.f, 0.f);
#pragma unroll
    for (int c = 0; c < 4; ++c) {
        float4 v = *(const float4*)(ppool + ((size_t)(b * 4 + c)) * DH + tid * 4);
        s.x += v.x; s.y += v.y; s.z += v.z; s.w += v.w;
    }
    float4 o = make_float4(s.x * inv, s.y * inv, s.z * inv, s.w * inv);
    *(float4*)(pooled + b * DH + tid * 4) = o;
}

// ---------------- GAT aggregation: MFMA + online softmax (flash-style) ------
// grid (NT/64, NH, NB). vt staged async via global_load_lds into a LINEAR
// XOR-swizzled [128][64] buffer (16B-chunk swizzle: lds slot cc holds global
// chunk cc^(d&7)); score phase hides the load latency; __syncthreads drains.
__global__ __launch_bounds__(256) void agg_mfma(
    const short* __restrict__ ht, const unsigned* __restrict__ mb,
    const float* __restrict__ s, const float* __restrict__ t,
    float* __restrict__ obuf)
{
    __shared__ __align__(16) short vt[128 * 64];   // 16 KB, swizzled linear
    __shared__ short at[64][72];
    __shared__ unsigned mrow[64][32];
    __shared__ float sv[64], alpha_s[64], lfin[64];
    int i0 = blockIdx.x * 64;
    int h = blockIdx.y, b = blockIdx.z;
    int tid = threadIdx.x;
    int lane = tid & 63, wave = tid >> 6;
    int quad = lane >> 4, lq = lane & 15;
    int wi = (wave >> 1) * 32;
    int wd = (wave & 1) * 64;
    if (tid < 64) sv[tid] = s[(size_t)(b * NH + h) * NT + i0 + tid];
#pragma unroll
    for (int s2 = 0; s2 < 2; ++s2) {
        int f = tid + s2 * 256;
        int ii2 = f >> 3, w4 = (f & 7) * 4;
        *(uint4*)&mrow[ii2][w4] =
            *(const uint4*)(mb + ((size_t)(b * NT + i0 + ii2)) * 32 + w4);
    }
    const float* tptr = t + (size_t)(b * NH + h) * NT;
    const short* hbase = ht + ((size_t)(b * NH + h) * DHD) * NT;
    // staging addresses: thread handles 4 16B chunks; chunk f = tid + s2*256,
    // d = f>>3, cc = f&7.  LDS dest linear f*16 (wave-uniform + lane*16);
    // global src pre-swizzled: chunk cc^(d&7) of row d.
    const short* gsrc[4];
    char* ldst[4];
#pragma unroll
    for (int s2 = 0; s2 < 4; ++s2) {
        int f = tid + s2 * 256;
        int d = f >> 3, cc = f & 7;
        gsrc[s2] = hbase + (size_t)d * NT + ((cc ^ (d & 7)) * 8);
        ldst[s2] = (char*)vt + wave * 1024 + s2 * 4096;
    }
    f32x4 acc[2][4];
#pragma unroll
    for (int i = 0; i < 2; ++i)
#pragma unroll
        for (int j = 0; j < 4; ++j) {
            f32x4 z = {0.f, 0.f, 0.f, 0.f};
            acc[i][j] = z;
        }
    int ii = tid >> 2;             // at row this thread fills
    int jq = (tid & 3) * 16;       // 16 j's per thread
    float m_run = -3e38f, l_run = 0.f;
    for (int j0 = 0; j0 < NT; j0 += 64) {
        __syncthreads();           // prev-iter vt/at reads done
        // issue async stage of vt for THIS tile; latency hides under scores
#if HAVE_GLL
#pragma unroll
        for (int s2 = 0; s2 < 4; ++s2) gll16(gsrc[s2] + j0, ldst[s2]);
#else
#pragma unroll
        for (int s2 = 0; s2 < 4; ++s2) {
            int f = tid + s2 * 256;
            short8 v8 = *(const short8*)(gsrc[s2] + j0);
            *(short8*)((char*)vt + (size_t)f * 16) = v8;
        }
#endif
        // scores for this thread's 16 j
        float vv[16];
        unsigned mw;
        float tmax = -3e38f;
        {
            mw = mrow[ii][(j0 + jq) >> 5] >> ((j0 + jq) & 31);
            float svv = sv[ii];
            float4 t0 = *(const float4*)(tptr + j0 + jq);
            float4 t1 = *(const float4*)(tptr + j0 + jq + 4);
            float4 t2 = *(const float4*)(tptr + j0 + jq + 8);
            float4 t3 = *(const float4*)(tptr + j0 + jq + 12);
            float tv16[16] = {t0.x, t0.y, t0.z, t0.w, t1.x, t1.y, t1.z, t1.w,
                              t2.x, t2.y, t2.z, t2.w, t3.x, t3.y, t3.z, t3.w};
#pragma unroll
            for (int e = 0; e < 16; ++e) {
                float v = svv + tv16[e];
                v = v > 0.f ? v : 0.2f * v;
                v = ((mw >> e) & 1) ? v : -1e9f;
                vv[e] = v;
                tmax = fmaxf(tmax, v);
            }
        }
        // reduce max over the 4 lanes of this row (consecutive lanes)
        tmax = fmaxf(tmax, __shfl_xor(tmax, 1, 64));
        tmax = fmaxf(tmax, __shfl_xor(tmax, 2, 64));
        float m_new = fmaxf(m_run, tmax);
        float al = __expf(m_run - m_new);   // first iter: exp(-inf) = 0
        float tsum = 0.f;
        short8 p0, p1;
#pragma unroll
        for (int e = 0; e < 8; ++e) {
            float w = ((mw >> e) & 1) ? __expf(vv[e] - m_new) : 0.f;
            tsum += w; p0[e] = f2bf(w);
        }
#pragma unroll
        for (int e = 0; e < 8; ++e) {
            float w = ((mw >> (8 + e)) & 1) ? __expf(vv[8 + e] - m_new) : 0.f;
            tsum += w; p1[e] = f2bf(w);
        }
        tsum += __shfl_xor(tsum, 1, 64);
        tsum += __shfl_xor(tsum, 2, 64);
        l_run = l_run * al + tsum;
        m_run = m_new;
        *(short8*)&at[ii][jq] = p0;
        *(short8*)&at[ii][jq + 8] = p1;
        if ((tid & 3) == 0) alpha_s[ii] = al;
        __syncthreads();   // drains gll16 (compiler vmcnt 0) + at visible
        // rescale acc by per-row alpha
#pragma unroll
        for (int i2 = 0; i2 < 2; ++i2)
#pragma unroll
            for (int r = 0; r < 4; ++r) {
                float arow = alpha_s[wi + i2 * 16 + quad * 4 + r];
#pragma unroll
                for (int j = 0; j < 4; ++j) acc[i2][j][r] *= arow;
            }
        // MFMA over this j-tile: 2 k-steps of 32, swizzle-corrected vt reads
        const char* vtb = (const char*)vt;
#pragma unroll
        for (int ks = 0; ks < 2; ++ks) {
            short8 af[2], bfr[4];
            af[0] = *(short8*)&at[wi + lq][ks * 32 + quad * 8];
            af[1] = *(short8*)&at[wi + 16 + lq][ks * 32 + quad * 8];
            int cc = ks * 4 + quad;
            int sx = (cc ^ (lq & 7)) * 16;
#pragma unroll
            for (int j = 0; j < 4; ++j)
                bfr[j] = *(const short8*)(vtb + (wd + j * 16 + lq) * 128 + sx);
#pragma unroll
            for (int i2 = 0; i2 < 2; ++i2)
#pragma unroll
                for (int j = 0; j < 4; ++j)
                    acc[i2][j] = __builtin_amdgcn_mfma_f32_16x16x32_bf16(
                        af[i2], bfr[j], acc[i2][j], 0, 0, 0);
        }
    }
    if ((tid & 3) == 0) lfin[ii] = l_run;
    __syncthreads();
#pragma unroll
    for (int i2 = 0; i2 < 2; ++i2) {
#pragma unroll
        for (int r = 0; r < 4; ++r) {
            int il = wi + i2 * 16 + quad * 4 + r;
            float inv = 1.0f / lfin[il];
            float* dst = obuf + ((size_t)(b * NT + i0 + il)) * DH + h * DHD + wd;
#pragma unroll
            for (int j = 0; j < 4; ++j)
                dst[j * 16 + lq] = acc[i2][j][r] * inv;
        }
    }
}

// ---------------- weighted pool partials (softmax of raw scores inline) -----
__global__ __launch_bounds__(256) void pool_part(
    const float* __restrict__ x, const float* __restrict__ scores,
    float* __restrict__ gpart)
{
    __shared__ float red[8];
    int p = blockIdx.x;
    int b = blockIdx.y;
    int tid = threadIdx.x;
    const float* sr = scores + (size_t)b * NT;
    float v[4];
    float mx = -3e38f;
#pragma unroll
    for (int k = 0; k < 4; ++k) { v[k] = sr[tid + k * 256]; mx = fmaxf(mx, v[k]); }
    float m = block_max1(mx, red);
    float ls = 0.f;
#pragma unroll
    for (int k = 0; k < 4; ++k) ls += expf(v[k] - m);
    float tot = block_sum1(ls, red + 4);
    float inv = 1.0f / tot;
    float a0 = 0, a1 = 0, a2 = 0, a3 = 0;
    for (int n = p * 128; n < (p + 1) * 128; ++n) {
        float wv = expf(sr[n] - m) * inv;
        float4 xv = *(const float4*)(x + ((size_t)(b * NT + n)) * DH + tid * 4);
        a0 += wv * xv.x; a1 += wv * xv.y; a2 += wv * xv.z; a3 += wv * xv.w;
    }
    float4 o = make_float4(a0, a1, a2, a3);
    *(float4*)(gpart + ((size_t)(b * 8 + p)) * DH + tid * 4) = o;
}

// ---------------- candidate scorer: partial GEMV over d-chunks + finisher --
__global__ __launch_bounds__(256) void scorer_part(
    const float* __restrict__ gpart, const float* __restrict__ W1,
    float* __restrict__ spart)
{
    __shared__ float gsh[128];
    int c = blockIdx.x, b = blockIdx.y;
    int tid = threadIdx.x;
    if (tid < 128) {
        int d = c * 128 + tid;
        float gv = 0.f;
#pragma unroll
        for (int p = 0; p < 8; ++p) gv += gpart[((size_t)(b * 8 + p)) * DH + d];
        gsh[tid] = gv;
    }
    __syncthreads();
    float acc[4] = {};
    for (int dd = 0; dd < 128; ++dd) {
        float gv = gsh[dd];
        const float* wr = W1 + (size_t)(c * 128 + dd) * DH;
#pragma unroll
        for (int cc = 0; cc < 4; ++cc) acc[cc] += gv * wr[tid + cc * 256];
    }
#pragma unroll
    for (int cc = 0; cc < 4; ++cc)
        spart[((size_t)(b * 8 + c)) * DH + tid + cc * 256] = acc[cc];
}
__global__ __launch_bounds__(256) void scorer_fin(
    const float* __restrict__ spart, const float* __restrict__ b1,
    const float* __restrict__ W2, const float* __restrict__ b2,
    float* __restrict__ out)
{
    __shared__ float red[4];
    int b = blockIdx.x;
    int tid = threadIdx.x;
    float part = 0.f;
#pragma unroll
    for (int cc = 0; cc < 4; ++cc) {
        int k = tid + cc * 256;
        float s = 0.f;
#pragma unroll
        for (int c = 0; c < 8; ++c) s += spart[((size_t)(b * 8 + c)) * DH + k];
        float u = s + b1[k];
        float inner = 0.7978845608028654f * (u + 0.044715f * u * u * u);
        float gel = 0.5f * u * (1.0f + tanhf(inner));
        part += gel * W2[k];
    }
    float tot = block_sum1(part, red);
    if (tid == 0) out[b] = tot + b2[0];
}

// ---------------- launch ----------------
extern "C" void kernel_launch(void* const* d_in, const int* in_sizes, int n_in,
                              void* d_out, int out_size, void* d_ws, size_t ws_size,
                              hipStream_t stream)
{
    const float* visual   = (const float*)d_in[0];
    const int*   q_ids    = (const int*)d_in[1];
    const int*   q_mask   = (const int*)d_in[2];
    const float* kg_feat  = (const float*)d_in[3];
    const int*   adj      = (const int*)d_in[4];
    const int*   ntypes   = (const int*)d_in[5];
    const float* vis_W    = (const float*)d_in[6];
    const float* vis_b    = (const float*)d_in[7];
    const float* vis_lng  = (const float*)d_in[8];
    const float* vis_lnb  = (const float*)d_in[9];
    const float* tok_emb  = (const float*)d_in[10];
    const float* q_W      = (const float*)d_in[11];
    const float* q_b      = (const float*)d_in[12];
    const float* q_lng    = (const float*)d_in[13];
    const float* q_lnb    = (const float*)d_in[14];
    const float* kg_W     = (const float*)d_in[15];
    const float* kg_b     = (const float*)d_in[16];
    const float* kg_lng   = (const float*)d_in[17];
    const float* kg_lnb   = (const float*)d_in[18];
    const float* type_emb = (const float*)d_in[19];
    const float* gat_W    = (const float*)d_in[20];
    const float* gat_b    = (const float*)d_in[21];
    const float* a_src    = (const float*)d_in[22];
    const float* a_dst    = (const float*)d_in[23];
    const float* gat_lng  = (const float*)d_in[24];
    const float* gat_lnb  = (const float*)d_in[25];
    const float* read_W   = (const float*)d_in[26];
    const float* read_b   = (const float*)d_in[27];
    const float* cs_W1    = (const float*)d_in[28];
    const float* cs_b1    = (const float*)d_in[29];
    const float* cs_W2    = (const float*)d_in[30];
    const float* cs_b2    = (const float*)d_in[31];
    float* out = (float*)d_out;

    float* ws = (float*)d_ws;
    const size_t NROW = (size_t)NB * NT;              // 8192
    float* x      = ws;                               // 8M floats
    float* obuf   = x + NROW * DH;                    // 8M floats
    float* sbuf   = obuf + NROW * DH;                 // 64K
    float* tbuf   = sbuf + NB * NH * NT;
    float* pooled = tbuf + NB * NH * NT;
    float* scores = pooled + NB * DH;
    float* gpart  = scores + NROW;
    float* ppool  = gpart + NB * 8 * DH;              // 32K floats
    float* pden   = ppool + NB * 4 * DH;              // 64 floats (32 used)
    float* spart  = pden + 64;                        // 64K floats
    short* wt_gat = (short*)(spart + NB * 8 * DH);    // 3M shorts
    short* ht     = wt_gat + (size_t)NLAYERS * DH * DH;   // 8M shorts
    unsigned* mb  = (unsigned*)(ht + (size_t)NB * NH * DHD * NT);  // 256K u32
    short* xb     = (short*)(mb + (size_t)NB * NT * 32);  // 8M shorts
    short* wt_vis = xb + NROW * DH;                   // 1024x2048
    short* wt_q   = wt_vis + (size_t)1024 * 2048;     // 1024x1024
    short* wt_kg  = wt_q + (size_t)1024 * 1024;       // 1024x320

    // 0. weight transpose-casts (gat stack batched) + adjacency bitmask
    transpose_cast<<<dim3(16, 32, 1), 256, 0, stream>>>(vis_W, wt_vis, DV, DH, DV, 0, 0);
    transpose_cast<<<dim3(16, 16, 1), 256, 0, stream>>>(q_W, wt_q, DH, DH, DH, 0, 0);
    transpose_cast<<<dim3(16, 5, 1), 256, 0, stream>>>(kg_W, wt_kg, DK, DH, 320, 0, 0);
    transpose_cast<<<dim3(16, 16, NLAYERS), 256, 0, stream>>>(
        gat_W, wt_gat, DH, DH, DH, (size_t)DH * DH, (size_t)DH * DH);
    bitmask_kernel<<<NB * NT, 256, 0, stream>>>(adj, mb);

    // 1. visual projection + LN (+type emb fused) -> x[:, 0:100]
    gemm_bias_mfma<<<dim3(8, 7), 256, 0, stream>>>(
        visual, wt_vis, vis_b, obuf, NB * NV, DH, DV, DV, DV);
    ln_scatter<<<NB * NV, 256, 0, stream>>>(obuf, x, vis_lng, vis_lnb,
        ntypes, type_emb, xb, NB * NV, NV, 0);

    // 2. text pool + proj + LN -> x[:, 100]
    qpool_part<<<dim3(NB, 4), 256, 0, stream>>>(tok_emb, q_ids, q_mask, ppool, pden);
    qpool_fin<<<NB, 256, 0, stream>>>(ppool, pden, pooled);
    gemm_bias_mfma<<<dim3(8, 1), 256, 0, stream>>>(
        pooled, wt_q, q_b, obuf, NB, DH, DH, DH, DH);
    ln_scatter<<<NB, 256, 0, stream>>>(obuf, x, q_lng, q_lnb,
        ntypes, type_emb, xb, NB, 1, NV);

    // 3. KG projection + LN -> x[:, 101:1024]
    gemm_bias_mfma<<<dim3(8, 58), 256, 0, stream>>>(
        kg_feat, wt_kg, kg_b, obuf, NB * NKG, DH, DK, 320, DK);
    ln_scatter<<<NB * NKG, 256, 0, stream>>>(obuf, x, kg_lng, kg_lnb,
        ntypes, type_emb, xb, NB * NKG, NKG, NV + 1);

    // 4. GAT layers (stats fused into agg via online softmax)
    for (int l = 0; l < NLAYERS; ++l) {
        const float* bl  = gat_b + (size_t)l * DH;
        const float* asl = a_src + (size_t)l * NH * DHD;
        const float* adl = a_dst + (size_t)l * NH * DHD;
        gemm_st_mfma<<<dim3(NH, 64), 256, 0, stream>>>(
            xb, wt_gat + (size_t)l * DH * DH, bl, asl, adl, ht, sbuf, tbuf);
        agg_mfma<<<dim3(16, NH, NB), 256, 0, stream>>>(
            ht, mb, sbuf, tbuf, obuf);
        ln_residual<<<NB * NT, 256, 0, stream>>>(x, obuf,
            gat_lng + (size_t)l * DH, gat_lnb + (size_t)l * DH, xb,
            read_W, read_b, (l == NLAYERS - 1) ? scores : nullptr);
    }

    // 5. readout + scorer (scores raw; pool_part does softmax inline)
    pool_part<<<dim3(8, NB), 256, 0, stream>>>(x, scores, gpart);
    scorer_part<<<dim3(8, NB), 256, 0, stream>>>(gpart, cs_W1, spart);
    scorer_fin<<<NB, 256, 0, stream>>>(spart, cs_b1, cs_W2, cs_b2, out);
}